// Round 6
// baseline (314.455 us; speedup 1.0000x reference)
//
#include <hip/hip_runtime.h>

// Reference constants
#define NUM_EMB    8192
#define EMB_DIM    512
#define BATCH_N    16384
#define BD         (BATCH_N * EMB_DIM)   // 8388608 elems in quantized (and diff)
#define TOTAL_OUT  (2 * BD + 1)          // 16777217 fp32 elems in d_out
#define NCHUNK     (TOTAL_OUT / 4)       // 4194304 full float4 chunks (+1 tail)
#define QCHUNK_END (BD / 4)              // 2097152: boundary chunk index
#define NTHREADS   256
#define NBLOCKS    4096
#define NTOTAL     (NBLOCKS * NTHREADS)  // 1048576 threads = 16384 waves

// Cross-block handoff for the fused loss reduction. g_partial overwritten
// every replay; g_done reset to 0 by the last block every replay (starts 0
// from .bss). This exact pattern passed correctness in round 2 (its
// regression there was the nontemporal stores, not the atomics).
__device__ float g_partial[NBLOCKS];
__device__ int   g_done;

// ---- Fused kernel: W^2 partial + gather + write, one dispatch. ----
// Wave w owns batch row b = w (16384 waves), writing chunks 128b..128b+127
// where chunk 128b+i = [row-b elem 4i-1 .. 4i+2] (i=0 borrows prev row's
// elem 511, a wave-uniform s_load). STRIDE-1 LANE MAPPING (validated round
// 5, -3us): lane l loads row-chunks l and l+64, stores output chunks cb+l
// and cb+64+l — every vector load/store is a fully-contiguous 1KB wave
// access. The +1 phase shift is one __shfl_up per half-row; lane 0 of the
// upper half borrows lane 63's v0.w.
// W^2: each thread loads exactly one float4 of W (4096*256*16B = 16MB),
// overlapped with the gather; per-block partial published with a release
// store; last-arriving block (agent-scope fetch_add) reduces and writes
// the loss chunk.
// NORMAL stores only: nontemporal stores measured 1.5x write amplification
// + ~10x throughput loss (round 2). Zero-stores stay in-kernel: a separate
// memset node cost +6us serial (round 3).
__global__ __launch_bounds__(NTHREADS) void vq_fused(const int* __restrict__ x,
        const float* __restrict__ W, float* __restrict__ out) {
    const int tid  = blockIdx.x * NTHREADS + threadIdx.x;
    const int lane = threadIdx.x & 63;
    const int wid  = threadIdx.x >> 6;
    float4* out4 = (float4*)out;

    // Wave-uniform batch row, forced into an SGPR (index chain -> s_loads).
    const int b  = __builtin_amdgcn_readfirstlane(tid >> 6);   // 0..16383
    const int k  = x[b];                        // s_load (uniform addr)
    const int kp = (b > 0) ? x[b - 1] : 0;      // s_load (uniform addr)

    // W^2 slice: independent, issues immediately (fills the x->R latency).
    const float4* W4 = (const float4*)W;
    float4 sw = W4[tid];

    // Gather: 2 contiguous 1KB wave loads, SGPR base.
    const float4* R = (const float4*)(W + k * EMB_DIM);
    float4 v0 = R[lane];                        // row elems 4l .. 4l+3
    float4 v1 = R[lane + 64];                   // row elems 256+4l .. 259+4l
    float p0 = W[kp * EMB_DIM + 511];           // s_load, broadcast

    // Diff region: 2097151 zero chunks, 2 per thread, contiguous
    // fire-and-forget stores issued while the loads are in flight.
#pragma unroll
    for (int z = 0; z < 2; ++z) {
        int c = QCHUNK_END + 1 + tid + z * NTOTAL;
        if (c < NCHUNK) out4[c] = make_float4(0.f, 0.f, 0.f, 0.f);
    }
    if (blockIdx.x == 1 && threadIdx.x == 0) {
        out[TOTAL_OUT - 1] = 0.0f;                       // odd tail diff elem
        float w = W[x[BATCH_N - 1] * EMB_DIM + 511];     // boundary chunk
        out4[QCHUNK_END] = make_float4(w, 0.f, 0.f, 0.f);
    }

    // W^2 partial reduce (VALU work under the in-flight gather).
    float s = sw.x*sw.x + sw.y*sw.y + sw.z*sw.z + sw.w*sw.w;
#pragma unroll
    for (int off = 32; off > 0; off >>= 1) s += __shfl_down(s, off, 64);
    __shared__ float ls[NTHREADS / 64];
    if (lane == 0) ls[wid] = s;

    // Row b: lane l covers chunks cb+l (lower half) and cb+64+l (upper).
    const int cb = 128 * b;
    {
        float pw = __shfl_up(v0.w, 1, 64);      // lane l-1's elem 4l-1
        float first = (lane == 0) ? p0 : pw;
        if (b != 0 || lane != 0)                // chunk 0 is the loss chunk
            out4[cb + lane] = make_float4(first, v0.x, v0.y, v0.z);
    }
    {
        float mid = __shfl(v0.w, 63, 64);       // row elem 255
        float pw  = __shfl_up(v1.w, 1, 64);     // lane l-1's elem 255+4l
        float first = (lane == 0) ? mid : pw;
        out4[cb + 64 + lane] = make_float4(first, v1.x, v1.y, v1.z);
    }

    // Publish block partial; LAST block to arrive computes the loss.
    // Device-scope atomics: per-XCD L2s are not cross-coherent (G16).
    __syncthreads();
    __shared__ int lastflag;
    if (threadIdx.x == 0) {
        float part = ls[0] + ls[1] + ls[2] + ls[3];
        __hip_atomic_store(&g_partial[blockIdx.x], part,
                           __ATOMIC_RELEASE, __HIP_MEMORY_SCOPE_AGENT);
        int t = __hip_atomic_fetch_add(&g_done, 1,
                                       __ATOMIC_ACQ_REL, __HIP_MEMORY_SCOPE_AGENT);
        lastflag = (t == NBLOCKS - 1);
    }
    __syncthreads();
    if (lastflag) {
        float s2 = 0.f;
        for (int i = threadIdx.x; i < NBLOCKS; i += NTHREADS)   // 16 indep loads
            s2 += __hip_atomic_load(&g_partial[i], __ATOMIC_RELAXED,
                                    __HIP_MEMORY_SCOPE_AGENT);
        __shared__ float red[NTHREADS];
        red[threadIdx.x] = s2;
        __syncthreads();
        for (int st = NTHREADS / 2; st > 0; st >>= 1) {
            if (threadIdx.x < st) red[threadIdx.x] += red[threadIdx.x + st];
            __syncthreads();
        }
        if (threadIdx.x == 0) {
            float loss = 0.25f * red[0];        // diff loss term is exactly 0
            int kk = x[0];
            float4 v = *(const float4*)(W + kk * EMB_DIM);
            out4[0] = make_float4(loss, v.x, v.y, v.z);
            __hip_atomic_store(&g_done, 0,      // reset for next graph replay
                               __ATOMIC_RELAXED, __HIP_MEMORY_SCOPE_AGENT);
        }
    }
}

extern "C" void kernel_launch(void* const* d_in, const int* in_sizes, int n_in,
                              void* d_out, int out_size, void* d_ws, size_t ws_size,
                              hipStream_t stream) {
    const int*   x = (const int*)d_in[0];    // int32 indices, 16384
    const float* W = (const float*)d_in[1];  // fp32 codebook, 8192x512
    float* out     = (float*)d_out;          // fp32: [loss | quantized | diff]

    vq_fused<<<NBLOCKS, NTHREADS, 0, stream>>>(x, W, out);
}

// Round 7
// 133.515 us; speedup vs baseline: 2.3552x; 2.3552x over previous
//
#include <hip/hip_runtime.h>

// Reference constants
#define NUM_EMB    8192
#define EMB_DIM    512
#define BATCH_N    16384
#define BD         (BATCH_N * EMB_DIM)   // 8388608 elems in quantized (and diff)
#define TOTAL_OUT  (2 * BD + 1)          // 16777217 fp32 elems in d_out
#define NCHUNK     (TOTAL_OUT / 4)       // 4194304 full float4 chunks (+1 tail)
#define QCHUNK_END (BD / 4)              // 2097152: boundary chunk index
#define NTHREADS   256
#define NBLOCKS    4096
#define NTOTAL     (NBLOCKS * NTHREADS)  // 1048576 threads = 16384 waves

// Cross-block handoff. ALL RELAXED ATOMICS — round-6 lesson: agent-scope
// release/acquire on gfx950 emit buffer_wbl2 / L2-invalidate (per-XCD L2s
// are non-coherent), and 4096 blocks' worth of full-L2 flushes turned the
// kernel latency-bound (264us @ 344 GB/s). Relaxed atomic RMWs execute at
// the coherence point with NO cache maintenance; visibility comes from
// per-location atomic coherence + an explicit vmcnt(0) between the partial
// publish and the counter increment (rocPRIM look-back idiom).
// g_partial overwritten every replay; g_done reset by the last block.
__device__ float g_partial[NBLOCKS];
__device__ int   g_done;

// ---- Fused kernel: W^2 partial + gather + write, one dispatch. ----
// Wave w owns batch row b = w (16384 waves), writing chunks 128b..128b+127
// where chunk 128b+i = [row-b elem 4i-1 .. 4i+2] (i=0 borrows prev row's
// elem 511, a wave-uniform s_load). STRIDE-1 LANE MAPPING (validated round
// 5, -3us): lane l loads row-chunks l and l+64, stores output chunks cb+l
// and cb+64+l — every vector load/store is a fully-contiguous 1KB wave
// access. The +1 phase shift is one __shfl_up per half-row; lane 0 of the
// upper half borrows lane 63's v0.w.
// W^2: each thread loads exactly one float4 of W (4096*256*16B = 16MB),
// overlapped with the store streams.
// NORMAL stores only: nontemporal stores measured 1.5x write amplification
// + ~10x throughput loss (round 2). Zero-stores stay in-kernel: a separate
// memset node cost +6us serial (round 3).
__global__ __launch_bounds__(NTHREADS) void vq_fused(const int* __restrict__ x,
        const float* __restrict__ W, float* __restrict__ out) {
    const int tid  = blockIdx.x * NTHREADS + threadIdx.x;
    const int lane = threadIdx.x & 63;
    const int wid  = threadIdx.x >> 6;
    float4* out4 = (float4*)out;

    // Wave-uniform batch row, forced into an SGPR (index chain -> s_loads).
    const int b  = __builtin_amdgcn_readfirstlane(tid >> 6);   // 0..16383
    const int k  = x[b];                        // s_load (uniform addr)
    const int kp = (b > 0) ? x[b - 1] : 0;      // s_load (uniform addr)

    // W^2 slice: independent, issues immediately (fills the x->R latency).
    const float4* W4 = (const float4*)W;
    float4 sw = W4[tid];

    // Gather: 2 contiguous 1KB wave loads, SGPR base.
    const float4* R = (const float4*)(W + k * EMB_DIM);
    float4 v0 = R[lane];                        // row elems 4l .. 4l+3
    float4 v1 = R[lane + 64];                   // row elems 256+4l .. 259+4l
    float p0 = W[kp * EMB_DIM + 511];           // s_load, broadcast

    // Diff region: 2097151 zero chunks, 2 per thread, contiguous
    // fire-and-forget stores issued while the loads are in flight.
#pragma unroll
    for (int z = 0; z < 2; ++z) {
        int c = QCHUNK_END + 1 + tid + z * NTOTAL;
        if (c < NCHUNK) out4[c] = make_float4(0.f, 0.f, 0.f, 0.f);
    }
    if (blockIdx.x == 1 && threadIdx.x == 0) {
        out[TOTAL_OUT - 1] = 0.0f;                       // odd tail diff elem
        float w = W[x[BATCH_N - 1] * EMB_DIM + 511];     // boundary chunk
        out4[QCHUNK_END] = make_float4(w, 0.f, 0.f, 0.f);
    }

    // W^2 partial reduce (VALU work under the in-flight loads).
    float s = sw.x*sw.x + sw.y*sw.y + sw.z*sw.z + sw.w*sw.w;
#pragma unroll
    for (int off = 32; off > 0; off >>= 1) s += __shfl_down(s, off, 64);
    __shared__ float ls[NTHREADS / 64];
    if (lane == 0) ls[wid] = s;

    // Row b: lane l covers chunks cb+l (lower half) and cb+64+l (upper).
    const int cb = 128 * b;
    {
        float pw = __shfl_up(v0.w, 1, 64);      // lane l-1's elem 4l-1
        float first = (lane == 0) ? p0 : pw;
        if (b != 0 || lane != 0)                // chunk 0 is the loss chunk
            out4[cb + lane] = make_float4(first, v0.x, v0.y, v0.z);
    }
    {
        float mid = __shfl(v0.w, 63, 64);       // row elem 255
        float pw  = __shfl_up(v1.w, 1, 64);     // lane l-1's elem 255+4l
        float first = (lane == 0) ? mid : pw;
        out4[cb + 64 + lane] = make_float4(first, v1.x, v1.y, v1.z);
    }

    // Publish block partial; LAST block to arrive computes the loss.
    // Relaxed-only protocol (no wbl2/inv):
    //   swap(g_partial[bid], part)  -- RMW, performed at coherence point
    //   s_waitcnt vmcnt(0)          -- swap complete before counter bump
    //   t = fetch_add(g_done, 1)    -- relaxed RMW
    //   last block: relaxed atomic loads of g_partial (coherence-point reads)
    __syncthreads();
    __shared__ int lastflag;
    if (threadIdx.x == 0) {
        float part = ls[0] + ls[1] + ls[2] + ls[3];
        __hip_atomic_exchange(&g_partial[blockIdx.x], part,
                              __ATOMIC_RELAXED, __HIP_MEMORY_SCOPE_AGENT);
        asm volatile("s_waitcnt vmcnt(0)" ::: "memory");
        int t = __hip_atomic_fetch_add(&g_done, 1,
                                       __ATOMIC_RELAXED, __HIP_MEMORY_SCOPE_AGENT);
        lastflag = (t == NBLOCKS - 1);
    }
    __syncthreads();
    if (lastflag) {
        float s2 = 0.f;
        for (int i = threadIdx.x; i < NBLOCKS; i += NTHREADS)   // 16 indep loads
            s2 += __hip_atomic_load(&g_partial[i], __ATOMIC_RELAXED,
                                    __HIP_MEMORY_SCOPE_AGENT);
        __shared__ float red[NTHREADS];
        red[threadIdx.x] = s2;
        __syncthreads();
        for (int st = NTHREADS / 2; st > 0; st >>= 1) {
            if (threadIdx.x < st) red[threadIdx.x] += red[threadIdx.x + st];
            __syncthreads();
        }
        if (threadIdx.x == 0) {
            float loss = 0.25f * red[0];        // diff loss term is exactly 0
            int kk = x[0];
            float4 v = *(const float4*)(W + kk * EMB_DIM);
            out4[0] = make_float4(loss, v.x, v.y, v.z);
            __hip_atomic_store(&g_done, 0,      // reset for next graph replay
                               __ATOMIC_RELAXED, __HIP_MEMORY_SCOPE_AGENT);
        }
    }
}

extern "C" void kernel_launch(void* const* d_in, const int* in_sizes, int n_in,
                              void* d_out, int out_size, void* d_ws, size_t ws_size,
                              hipStream_t stream) {
    const int*   x = (const int*)d_in[0];    // int32 indices, 16384
    const float* W = (const float*)d_in[1];  // fp32 codebook, 8192x512
    float* out     = (float*)d_out;          // fp32: [loss | quantized | diff]

    vq_fused<<<NBLOCKS, NTHREADS, 0, stream>>>(x, W, out);
}

// Round 9
// 96.288 us; speedup vs baseline: 3.2658x; 1.3866x over previous
//
#include <hip/hip_runtime.h>

// Reference constants
#define NUM_EMB    8192
#define EMB_DIM    512
#define BATCH_N    16384
#define BD         (BATCH_N * EMB_DIM)   // 8388608 elems in quantized (and diff)
#define TOTAL_OUT  (2 * BD + 1)          // 16777217 fp32 elems in d_out
#define NCHUNK     (TOTAL_OUT / 4)       // 4194304 full float4 chunks (+1 tail)
#define QCHUNK_END (BD / 4)              // 2097152: boundary chunk index
#define NTHREADS   256
#define NB_SUM     2048
#define NTOT_SUM   (NB_SUM * NTHREADS)   // 524288 threads = 8192 waves
#define NB_GATHER  4096                  // gather blocks: 16384 waves, 1 row each
#define NB_ZERO    2048                  // pure zero-fill blocks
#define NB_WR      (NB_GATHER + NB_ZERO) // 6144 blocks in vq_write
#define NTOT_Z     (NB_ZERO * NTHREADS)  // 524288 zero-fill threads

// K1->K2 handoff via plain stores + stream-order kernel boundary
// (validated). NO cross-block atomics anywhere: round 6 showed agent-scope
// release/acquire = full-L2 writeback/invalidate per block (264us); round 7
// showed even relaxed same-line RMWs serialize ~40us across 4096 blocks.
// Fusion ceiling was only ~4us anyway (vq_sum + gap). Split is final.
__device__ float g_partial[NB_SUM];

// ---- K1: per-block partial sums of W^2 (16 MB fp32 stream, ~3 us). Also
// warms L2/L3 with W right before the gather kernel. ----
__global__ __launch_bounds__(NTHREADS) void vq_sum(const float* __restrict__ W) {
    int tid = blockIdx.x * NTHREADS + threadIdx.x;
    const float4* W4 = (const float4*)W;
    float4 a = W4[tid];
    float4 b = W4[tid + NTOT_SUM];
    float s = a.x*a.x + a.y*a.y + a.z*a.z + a.w*a.w
            + b.x*b.x + b.y*b.y + b.z*b.z + b.w*b.w;
#pragma unroll
    for (int off = 32; off > 0; off >>= 1) s += __shfl_down(s, off, 64);
    __shared__ float ls[NTHREADS / 64];
    if ((threadIdx.x & 63) == 0) ls[threadIdx.x >> 6] = s;
    __syncthreads();
    if (threadIdx.x == 0) g_partial[blockIdx.x] = ls[0] + ls[1] + ls[2] + ls[3];
}

// ---- K2: specialized writer, one dispatch, two block roles. ----
// Blocks [0, NB_GATHER): gather blocks. Wave w owns batch row b = w
// (16384 waves), writing chunks 128b..128b+127 where chunk 128b+i =
// [row-b elem 4i-1 .. 4i+2] (i=0 borrows prev row's elem 511, a
// wave-uniform s_load). STRIDE-1 LANE MAPPING (validated round 5, -3us):
// lane l loads row-chunks l and l+64, stores output chunks cb+l and
// cb+64+l — every vector load/store is a fully-contiguous 1KB wave access.
// The +1 phase shift is one __shfl_up per half-row; lane 0 of the upper
// half borrows lane 63's v0.w.
// Blocks [NB_GATHER, NB_WR): pure zero-fill blocks for the diff region —
// no loads at all, fill-kernel-shaped store stream (the rocclr fill proves
// pure-store waves sustain ~6.2 TB/s vs ~4.8 for our old mixed stream).
// Both roles run concurrently in ONE dispatch (round 3 showed a serial
// memset node costs +6us; this overlaps instead).
// NORMAL stores only: nontemporal stores measured 1.5x write amplification
// + ~10x throughput loss (round 2).
__global__ __launch_bounds__(NTHREADS) void vq_write(const int* __restrict__ x,
        const float* __restrict__ W, float* __restrict__ out) {
    float4* out4 = (float4*)out;

    // ---- Zero-fill role: contiguous fire-and-forget stores, then exit. ----
    if (blockIdx.x >= NB_GATHER) {
        const int zt = (blockIdx.x - NB_GATHER) * NTHREADS + threadIdx.x;
#pragma unroll
        for (int z = 0; z < 4; ++z) {
            int c = QCHUNK_END + 1 + zt + z * NTOT_Z;
            if (c < NCHUNK) out4[c] = make_float4(0.f, 0.f, 0.f, 0.f);
        }
        return;
    }

    // ---- Gather role. ----
    const int tid  = blockIdx.x * NTHREADS + threadIdx.x;
    const int lane = threadIdx.x & 63;

    // Wave-uniform batch row, forced into an SGPR (index chain -> s_loads).
    const int b  = __builtin_amdgcn_readfirstlane(tid >> 6);   // 0..16383
    const int k  = x[b];                        // s_load (uniform addr)
    const int kp = (b > 0) ? x[b - 1] : 0;      // s_load (uniform addr)

    // Gather: 2 contiguous 1KB wave loads, SGPR base.
    const float4* R = (const float4*)(W + k * EMB_DIM);
    float4 v0 = R[lane];                        // row elems 4l .. 4l+3
    float4 v1 = R[lane + 64];                   // row elems 256+4l .. 259+4l
    float p0 = W[kp * EMB_DIM + 511];           // s_load, broadcast

    if (blockIdx.x == 1 && threadIdx.x == 0) {
        out[TOTAL_OUT - 1] = 0.0f;                       // odd tail diff elem
        float w = W[x[BATCH_N - 1] * EMB_DIM + 511];     // boundary chunk
        out4[QCHUNK_END] = make_float4(w, 0.f, 0.f, 0.f);
    }

    const int cb = 128 * b;
    // Lower half: chunk cb+l = [elem 4l-1, 4l, 4l+1, 4l+2].
    {
        float pw = __shfl_up(v0.w, 1, 64);      // lane l-1's elem 4l-1
        float first = (lane == 0) ? p0 : pw;
        if (b != 0 || lane != 0)                // chunk 0 is the loss chunk
            out4[cb + lane] = make_float4(first, v0.x, v0.y, v0.z);
    }
    // Upper half: chunk cb+64+l = [elem 255+4l, 256+4l, 257+4l, 258+4l].
    {
        float mid = __shfl(v0.w, 63, 64);       // row elem 255
        float pw  = __shfl_up(v1.w, 1, 64);     // lane l-1's elem 255+4l
        float first = (lane == 0) ? mid : pw;
        out4[cb + 64 + lane] = make_float4(first, v1.x, v1.y, v1.z);
    }

    // Block 0: reduce vq_sum's partials -> loss, sole writer of chunk 0.
    if (blockIdx.x == 0) {
        __shared__ float red[NTHREADS];
        float s = 0.0f;
        for (int i = threadIdx.x; i < NB_SUM; i += NTHREADS) s += g_partial[i];
        red[threadIdx.x] = s;
        __syncthreads();
        for (int st = NTHREADS / 2; st > 0; st >>= 1) {
            if (threadIdx.x < st) red[threadIdx.x] += red[threadIdx.x + st];
            __syncthreads();
        }
        if (threadIdx.x == 0) {
            float loss = 0.25f * red[0];        // diff loss term is exactly 0
            int kk = x[0];
            float4 v = *(const float4*)(W + kk * EMB_DIM);
            out4[0] = make_float4(loss, v.x, v.y, v.z);
        }
    }
}

extern "C" void kernel_launch(void* const* d_in, const int* in_sizes, int n_in,
                              void* d_out, int out_size, void* d_ws, size_t ws_size,
                              hipStream_t stream) {
    const int*   x = (const int*)d_in[0];    // int32 indices, 16384
    const float* W = (const float*)d_in[1];  // fp32 codebook, 8192x512
    float* out     = (float*)d_out;          // fp32: [loss | quantized | diff]

    vq_sum<<<NB_SUM, NTHREADS, 0, stream>>>(W);
    vq_write<<<NB_WR, NTHREADS, 0, stream>>>(x, W, out);
}

// Round 10
// 93.028 us; speedup vs baseline: 3.3802x; 1.0350x over previous
//
#include <hip/hip_runtime.h>

// Reference constants
#define NUM_EMB    8192
#define EMB_DIM    512
#define BATCH_N    16384
#define BD         (BATCH_N * EMB_DIM)   // 8388608 elems in quantized (and diff)
#define TOTAL_OUT  (2 * BD + 1)          // 16777217 fp32 elems in d_out
#define NCHUNK     (TOTAL_OUT / 4)       // 4194304 full float4 chunks (+1 tail)
#define QCHUNK_END (BD / 4)              // 2097152: boundary chunk index
#define NTHREADS   256
#define NB_SUM     2048
#define NTOT_SUM   (NB_SUM * NTHREADS)   // 524288 threads = 8192 waves
#define NB_WR      4096
#define NTOT_WR    (NB_WR * NTHREADS)    // 1048576 threads = 16384 waves

// K1->K2 handoff via plain stores + stream-order kernel boundary.
// FINAL-FORM NOTES (session ledger):
//  - NO cross-block atomics: agent-scope release/acquire = full-L2
//    writeback/invalidate per block on gfx950 (round 6: 264us); even
//    relaxed same-line RMWs serialize ~40us across 4096 blocks (round 7).
//  - NO nontemporal stores: 1.5x write amplification + ~10x store
//    throughput loss, bypasses TCC write-combining (round 2).
//  - NO separate memset node for zeros: +6us serial (round 3); zeros are
//    ~free when overlapped inside the gather kernel (rounds 0/3/9).
//  - NO block specialization for zeros: neutral-to-worse (round 9).
//  - Stride-1 lane mapping: -3us, fully-covered cache lines (round 5).
__device__ float g_partial[NB_SUM];

// ---- K1: per-block partial sums of W^2 (16 MB fp32 stream, ~2.7 us =
// HBM floor). Also warms L2/L3 with W right before the gather kernel. ----
__global__ __launch_bounds__(NTHREADS) void vq_sum(const float* __restrict__ W) {
    int tid = blockIdx.x * NTHREADS + threadIdx.x;
    const float4* W4 = (const float4*)W;
    float4 a = W4[tid];
    float4 b = W4[tid + NTOT_SUM];
    float s = a.x*a.x + a.y*a.y + a.z*a.z + a.w*a.w
            + b.x*b.x + b.y*b.y + b.z*b.z + b.w*b.w;
#pragma unroll
    for (int off = 32; off > 0; off >>= 1) s += __shfl_down(s, off, 64);
    __shared__ float ls[NTHREADS / 64];
    if ((threadIdx.x & 63) == 0) ls[threadIdx.x >> 6] = s;
    __syncthreads();
    if (threadIdx.x == 0) g_partial[blockIdx.x] = ls[0] + ls[1] + ls[2] + ls[3];
}

// ---- K2: row-streaming writer, ONE batch row per wave (16384 waves). ----
// Wave w owns batch row b = w, writing chunks 128b..128b+127 where chunk
// 128b+i = [row-b elem 4i-1 .. 4i+2] (i=0 borrows prev row's elem 511,
// a wave-uniform s_load). STRIDE-1 LANE MAPPING: lane l loads row-chunks
// l and l+64, stores output chunks cb+l and cb+64+l — every vector
// load/store is a fully-contiguous 1KB wave access. The +1 phase shift is
// one __shfl_up per half-row; lane 0 of the upper half borrows lane 63's
// v0.w. Index chain scalarized (readfirstlane -> s_loads).
__global__ __launch_bounds__(NTHREADS) void vq_write(const int* __restrict__ x,
        const float* __restrict__ W, float* __restrict__ out) {
    const int tid  = blockIdx.x * NTHREADS + threadIdx.x;
    const int lane = threadIdx.x & 63;
    float4* out4 = (float4*)out;

    // Wave-uniform batch row, forced into an SGPR (index chain -> s_loads).
    const int b  = __builtin_amdgcn_readfirstlane(tid >> 6);   // 0..16383
    const int k  = x[b];                        // s_load (uniform addr)
    const int kp = (b > 0) ? x[b - 1] : 0;      // s_load (uniform addr)

    // Gather issued first: 2 contiguous 1KB wave loads, SGPR base.
    const float4* R = (const float4*)(W + k * EMB_DIM);
    float4 v0 = R[lane];                        // row elems 4l .. 4l+3
    float4 v1 = R[lane + 64];                   // row elems 256+4l .. 259+4l
    float p0 = W[kp * EMB_DIM + 511];           // s_load, broadcast

    // Diff region: 2097151 zero chunks, 2 per thread, contiguous
    // fire-and-forget stores issued while the gather is in flight.
#pragma unroll
    for (int z = 0; z < 2; ++z) {
        int c = QCHUNK_END + 1 + tid + z * NTOT_WR;
        if (c < NCHUNK) out4[c] = make_float4(0.f, 0.f, 0.f, 0.f);
    }
    if (blockIdx.x == 1 && threadIdx.x == 0) {
        out[TOTAL_OUT - 1] = 0.0f;                       // odd tail diff elem
        float w = W[x[BATCH_N - 1] * EMB_DIM + 511];     // boundary chunk
        out4[QCHUNK_END] = make_float4(w, 0.f, 0.f, 0.f);
    }

    const int cb = 128 * b;
    // Lower half: chunk cb+l = [elem 4l-1, 4l, 4l+1, 4l+2].
    {
        float pw = __shfl_up(v0.w, 1, 64);      // lane l-1's elem 4l-1
        float first = (lane == 0) ? p0 : pw;
        if (b != 0 || lane != 0)                // chunk 0 is the loss chunk
            out4[cb + lane] = make_float4(first, v0.x, v0.y, v0.z);
    }
    // Upper half: chunk cb+64+l = [elem 255+4l, 256+4l, 257+4l, 258+4l].
    {
        float mid = __shfl(v0.w, 63, 64);       // row elem 255
        float pw  = __shfl_up(v1.w, 1, 64);     // lane l-1's elem 255+4l
        float first = (lane == 0) ? mid : pw;
        out4[cb + 64 + lane] = make_float4(first, v1.x, v1.y, v1.z);
    }

    // Block 0: reduce vq_sum's partials -> loss, sole writer of chunk 0.
    if (blockIdx.x == 0) {
        __shared__ float red[NTHREADS];
        float s = 0.0f;
        for (int i = threadIdx.x; i < NB_SUM; i += NTHREADS) s += g_partial[i];
        red[threadIdx.x] = s;
        __syncthreads();
        for (int st = NTHREADS / 2; st > 0; st >>= 1) {
            if (threadIdx.x < st) red[threadIdx.x] += red[threadIdx.x + st];
            __syncthreads();
        }
        if (threadIdx.x == 0) {
            float loss = 0.25f * red[0];        // diff loss term is exactly 0
            int kk = x[0];
            float4 v = *(const float4*)(W + kk * EMB_DIM);
            out4[0] = make_float4(loss, v.x, v.y, v.z);
        }
    }
}

extern "C" void kernel_launch(void* const* d_in, const int* in_sizes, int n_in,
                              void* d_out, int out_size, void* d_ws, size_t ws_size,
                              hipStream_t stream) {
    const int*   x = (const int*)d_in[0];    // int32 indices, 16384
    const float* W = (const float*)d_in[1];  // fp32 codebook, 8192x512
    float* out     = (float*)d_out;          // fp32: [loss | quantized | diff]

    vq_sum<<<NB_SUM, NTHREADS, 0, stream>>>(W);
    vq_write<<<NB_WR, NTHREADS, 0, stream>>>(x, W, out);
}